// Round 3
// baseline (363.407 us; speedup 1.0000x reference)
//
#include <hip/hip_runtime.h>
#include <math.h>

// Codebook argmin via split-bf16 MFMA, barrier-free K-loop.
// cross = xh*ch + xh*cl + xl*ch  (3x v_mfma_f32_32x32x16_bf16).
// A (cluster frags) loaded straight from L2-resident ws (coalesced dwordx4,
// frag layout = base + lane*16). B (x) loaded per-lane from global and split
// hi/lo in-register (truncation split, err ~6e-4 << MARGIN). No LDS / no
// __syncthreads in the K-loop -> compiler free to pipeline with vmcnt(N).
// Epilogue: per-lane top-2 over 64 clusters, LDS combine, fp64 re-check of
// near-ties (gap < MARGIN).

#define NK   512
#define NC   512
#define NHW  4096
#define MARGIN 0.02f

typedef unsigned short u16;
typedef __attribute__((ext_vector_type(8)))  short  short8;
typedef __attribute__((ext_vector_type(16))) float  f32x16;

__device__ __forceinline__ u16 f2bf_rne(float f) {
    unsigned u = __builtin_bit_cast(unsigned, f);
    u += 0x7FFFu + ((u >> 16) & 1u);
    return (u16)(u >> 16);
}
__device__ __forceinline__ float bf2f(u16 h) {
    unsigned u = ((unsigned)h) << 16;
    return __builtin_bit_cast(float, u);
}

// wcc frag layout: [ch 32][unit 32][lane 64][8 bf16]; unit u<16 = hi plane of
// m-tile u, u>=16 = lo plane of m-tile u-16. lane ls: cluster k = mt*32+(ls&31),
// channels c = ch*16 + (ls>>5)*8 + j.
// One thread per output ushort8 -> perfectly coalesced 16B/lane writes.
__global__ __launch_bounds__(256) void prep_pack(const float* __restrict__ cc,
                                                 u16* __restrict__ wcc) {
    const int g  = blockIdx.x * 256 + threadIdx.x;   // 65536 total
    const int ls = g & 63;
    const int u  = (g >> 6) & 31;
    const int ch = g >> 11;
    const int plane = u >> 4;
    const int mt    = u & 15;
    const int k  = mt * 32 + (ls & 31);
    const int c0 = ch * 16 + (ls >> 5) * 8;
    const float* row = cc + (size_t)k * NC + c0;
    short8 v;
    #pragma unroll
    for (int j = 0; j < 8; ++j) {
        float f = row[j];
        u16 h = f2bf_rne(f);
        v[j] = plane ? (short)f2bf_rne(f - bf2f(h)) : (short)h;
    }
    *(short8*)(wcc + (size_t)g * 8) = v;
}

__global__ __launch_bounds__(256) void prep_shalf(const float* __restrict__ cc,
                                                  float* __restrict__ shalf) {
    const int k    = blockIdx.x * 4 + (threadIdx.x >> 6);
    const int lane = threadIdx.x & 63;
    const float4* row = (const float4*)(cc + (size_t)k * NC);
    float s = 0.f;
    #pragma unroll
    for (int i = 0; i < 2; ++i) {
        float4 v = row[lane + i * 64];
        s = fmaf(v.x, v.x, s); s = fmaf(v.y, v.y, s);
        s = fmaf(v.z, v.z, s); s = fmaf(v.w, v.w, s);
    }
    #pragma unroll
    for (int off = 32; off > 0; off >>= 1) s += __shfl_down(s, off, 64);
    if (lane == 0) shalf[k] = 0.5f * s;
}

__global__ __launch_bounds__(256, 2) void codebook_mfma(
        const float* __restrict__ x,
        const float* __restrict__ cc,
        const u16* __restrict__ wcc,
        const float* __restrict__ shalf,
        int* __restrict__ out)
{
    __shared__ float sh_s[NK];          // 2KB
    __shared__ float cand_v[64 * 8];    // 2KB
    __shared__ float cand_s[64 * 8];    // 2KB
    __shared__ int   cand_k[64 * 8];    // 2KB
    __shared__ float xcol[NC];          // 2KB
    __shared__ double dvv[256];         // 2KB
    __shared__ int    dii[256];         // 1KB
    __shared__ int    flagsh[64];
    __shared__ int    bestk_sh[64];

    const int tid  = threadIdx.x;
    const int w    = tid >> 6;
    const int lane = tid & 63;

    const int gp0 = blockIdx.x * 64;            // 4096 % 64 == 0
    const float* xb = x + (size_t)(gp0 >> 12) * (NC * NHW) + (gp0 & (NHW - 1));

    sh_s[tid]       = shalf[tid];
    sh_s[tid + 256] = shalf[tid + 256];

    f32x16 acc[4][2] = {};

    const int khalf = lane >> 5;                // channel half within chunk
    const float* xbase = xb + (lane & 31);      // + c*NHW + nt*32

    // prefetch x floats for chunk 0
    float nf[16];
    #pragma unroll
    for (int nt = 0; nt < 2; ++nt)
        #pragma unroll
        for (int j = 0; j < 8; ++j)
            nf[nt * 8 + j] = xbase[(size_t)(khalf * 8 + j) * NHW + nt * 32];

    for (int ch = 0; ch < 32; ++ch) {
        float cf[16];
        #pragma unroll
        for (int i = 0; i < 16; ++i) cf[i] = nf[i];
        if (ch < 31) {
            #pragma unroll
            for (int nt = 0; nt < 2; ++nt)
                #pragma unroll
                for (int j = 0; j < 8; ++j)
                    nf[nt * 8 + j] =
                        xbase[(size_t)((ch + 1) * 16 + khalf * 8 + j) * NHW + nt * 32];
        }
        // A frags straight from L2-resident ws (coalesced: base + lane*16)
        short8 ah[4], al[4];
        #pragma unroll
        for (int mt = 0; mt < 4; ++mt) {
            const int gm = w * 4 + mt;
            ah[mt] = *(const short8*)(wcc + ((size_t)(ch * 32 + gm)      * 64 + lane) * 8);
            al[mt] = *(const short8*)(wcc + ((size_t)(ch * 32 + 16 + gm) * 64 + lane) * 8);
        }
        // split x hi/lo in-register (truncation split)
        short8 bh[2], bl[2];
        #pragma unroll
        for (int nt = 0; nt < 2; ++nt)
            #pragma unroll
            for (int j = 0; j < 8; ++j) {
                float f = cf[nt * 8 + j];
                unsigned ub = __builtin_bit_cast(unsigned, f);
                float hf = __builtin_bit_cast(float, ub & 0xFFFF0000u);
                float r  = f - hf;
                bh[nt][j] = (short)(ub >> 16);
                bl[nt][j] = (short)(__builtin_bit_cast(unsigned, r) >> 16);
            }
        #pragma unroll
        for (int mt = 0; mt < 4; ++mt)
            #pragma unroll
            for (int nt = 0; nt < 2; ++nt) {
                acc[mt][nt] = __builtin_amdgcn_mfma_f32_32x32x16_bf16(ah[mt], bh[nt], acc[mt][nt], 0, 0, 0);
                acc[mt][nt] = __builtin_amdgcn_mfma_f32_32x32x16_bf16(al[mt], bh[nt], acc[mt][nt], 0, 0, 0);
                acc[mt][nt] = __builtin_amdgcn_mfma_f32_32x32x16_bf16(ah[mt], bl[nt], acc[mt][nt], 0, 0, 0);
            }
    }

    // ---- epilogue ----
    const int qb = lane >> 5;
    #pragma unroll
    for (int nt = 0; nt < 2; ++nt) {
        float best = -INFINITY, sec = -INFINITY;
        int bk = 0;
        #pragma unroll
        for (int mt = 0; mt < 4; ++mt) {
            const int kbase = w * 128 + mt * 32 + 4 * qb;
            #pragma unroll
            for (int reg = 0; reg < 16; ++reg) {
                const int k = kbase + (reg & 3) + 8 * (reg >> 2);
                const float v = acc[mt][nt][reg] - sh_s[k];
                if (v > best) { sec = best; best = v; bk = k; }
                else if (v > sec) sec = v;
            }
        }
        const int pc   = nt * 32 + (lane & 31);
        const int slot = w * 2 + qb;
        cand_v[pc * 8 + slot] = best;
        cand_s[pc * 8 + slot] = sec;
        cand_k[pc * 8 + slot] = bk;
    }
    __syncthreads();

    if (tid < 64) {
        float best = -INFINITY, sec = -INFINITY;
        int bk = 1 << 30;
        #pragma unroll
        for (int s = 0; s < 8; ++s) {
            float v  = cand_v[tid * 8 + s];
            float v2 = cand_s[tid * 8 + s];
            int  kk  = cand_k[tid * 8 + s];
            if (v > best || (v == best && kk < bk)) {
                sec = fmaxf(sec, best);
                best = v; bk = kk;
            } else sec = fmaxf(sec, v);
            sec = fmaxf(sec, v2);
        }
        bestk_sh[tid] = bk;
        flagsh[tid] = (best - sec < MARGIN) ? 1 : 0;
    }
    __syncthreads();

    // fp64 full re-check for near-tie pixels (rare)
    for (int pix = 0; pix < 64; ++pix) {
        if (!flagsh[pix]) continue;              // uniform (LDS) branch
        for (int c = tid; c < NC; c += 256)
            xcol[c] = xb[(size_t)c * NHW + pix];
        __syncthreads();
        double bd = 1e300;
        int bkk = 1 << 30;
        #pragma unroll
        for (int r = 0; r < 2; ++r) {
            const int k = tid + r * 256;
            const float4* crow = (const float4*)(cc + (size_t)k * NC);
            const float4* xc4  = (const float4*)xcol;
            double d = 0.0;
            for (int c4 = 0; c4 < NC / 4; ++c4) {
                float4 cv = crow[c4], xv = xc4[c4];
                double d0 = (double)xv.x - (double)cv.x;
                double d1 = (double)xv.y - (double)cv.y;
                double d2 = (double)xv.z - (double)cv.z;
                double d3 = (double)xv.w - (double)cv.w;
                d = fma(d0, d0, d); d = fma(d1, d1, d);
                d = fma(d2, d2, d); d = fma(d3, d3, d);
            }
            if (d < bd || (d == bd && k < bkk)) { bd = d; bkk = k; }
        }
        dvv[tid] = bd; dii[tid] = bkk;
        __syncthreads();
        for (int srd = 128; srd > 0; srd >>= 1) {
            if (tid < srd) {
                double ov = dvv[tid + srd]; int oi = dii[tid + srd];
                if (ov < dvv[tid] || (ov == dvv[tid] && oi < dii[tid])) {
                    dvv[tid] = ov; dii[tid] = oi;
                }
            }
            __syncthreads();
        }
        if (tid == 0) bestk_sh[pix] = dii[0];
        __syncthreads();
    }

    if (tid < 64) out[gp0 + tid] = bestk_sh[tid];
}

extern "C" void kernel_launch(void* const* d_in, const int* in_sizes, int n_in,
                              void* d_out, int out_size, void* d_ws, size_t ws_size,
                              hipStream_t stream) {
    const float* x  = (const float*)d_in[0];   // (16, 512, 64, 64) f32
    const float* cc = (const float*)d_in[1];   // (1, 512, 512, 1, 1) f32
    int* out = (int*)d_out;                    // (16, 1, 64, 64) int32

    float* shalf = (float*)d_ws;               // 512 floats
    u16*   wcc   = (u16*)(shalf + NK);         // 1MB frag-ordered hi/lo bf16

    prep_shalf<<<NK / 4, 256, 0, stream>>>(cc, shalf);
    prep_pack<<<(32 * 32 * 64) / 256, 256, 0, stream>>>(cc, wcc);
    codebook_mfma<<<(16 * NHW) / 64, 256, 0, stream>>>(x, cc, wcc, shalf, out);
}